// Round 1
// baseline (723.691 us; speedup 1.0000x reference)
//
#include <hip/hip_runtime.h>

#define NEG_SLOPE 0.2f

__device__ __forceinline__ float lrelu(float x) {
    return x > 0.f ? x : NEG_SLOPE * x;
}

// ---------------------------------------------------------------------------
// init: out[n*32+d] = mean_h bias[h*32+d];  s[] = 0
// ---------------------------------------------------------------------------
__global__ void init_kernel(const float* __restrict__ bias,
                            float* __restrict__ out,
                            float* __restrict__ s, int N) {
    int t = blockIdx.x * 256 + threadIdx.x;
    if (t < N * 4) s[t] = 0.f;
    if (t >= N * 32) return;
    int d = t & 31;
    out[t] = 0.25f * (bias[d] + bias[32 + d] + bias[64 + d] + bias[96 + d]);
}

// ---------------------------------------------------------------------------
// GEMM: h[N,128] = feat[N,128] @ W[128,128]  (fp32, vector ALU)
// Block: 128 rows x 128 cols, 256 threads, 8x8 register tile per thread.
// W fully staged in LDS (64 KB); feat tile staged with stride 132 (pad).
// Bank-conflict-free: a-reads strided rows (ty + i*16), w-reads wave-uniform.
// ---------------------------------------------------------------------------
__global__ __launch_bounds__(256, 1) void gemm_kernel(
    const float* __restrict__ feat, const float* __restrict__ Wm,
    float* __restrict__ h, int N) {
    __shared__ float sW[128 * 128];   // 64 KB, k-major: sW[k*128+c]
    __shared__ float sF[128 * 132];   // 67.6 KB, padded stride

    const int t = threadIdx.x;
    const int row0 = blockIdx.x * 128;

    // stage W (exact flat copy, row-major [k][c])
    {
        const float4* s4 = (const float4*)Wm;
        float4* d4 = (float4*)sW;
#pragma unroll
        for (int i = 0; i < 16; ++i) d4[t + i * 256] = s4[t + i * 256];
    }
    // stage feat rows row0..row0+127 into padded sF
    {
#pragma unroll
        for (int i = 0; i < 16; ++i) {
            int idx = t + i * 256;      // float4 index, 4096 total
            int r = idx >> 5;           // 32 float4 per row
            int c = (idx & 31) * 4;
            float4 v = make_float4(0.f, 0.f, 0.f, 0.f);
            if (row0 + r < N)
                v = *(const float4*)(feat + (size_t)(row0 + r) * 128 + c);
            *(float4*)(&sF[r * 132 + c]) = v;
        }
    }
    __syncthreads();

    const int tx = t & 15;    // col group
    const int ty = t >> 4;    // row group (0..15)
    float acc[8][8];
#pragma unroll
    for (int i = 0; i < 8; ++i)
#pragma unroll
        for (int j = 0; j < 8; ++j) acc[i][j] = 0.f;

    for (int k = 0; k < 128; ++k) {
        float a[8], w[8];
#pragma unroll
        for (int i = 0; i < 8; ++i) a[i] = sF[(ty + i * 16) * 132 + k];
#pragma unroll
        for (int j = 0; j < 8; ++j) w[j] = sW[k * 128 + tx + j * 16];
#pragma unroll
        for (int i = 0; i < 8; ++i)
#pragma unroll
            for (int j = 0; j < 8; ++j) acc[i][j] = fmaf(a[i], w[j], acc[i][j]);
    }

#pragma unroll
    for (int i = 0; i < 8; ++i) {
        int r = row0 + ty + i * 16;
        if (r < N) {
#pragma unroll
            for (int j = 0; j < 8; ++j)
                h[(size_t)r * 128 + tx + j * 16] = acc[i][j];
        }
    }
}

// ---------------------------------------------------------------------------
// el/er: per (node, head) 32-dim dot with attn_l / attn_r
// ---------------------------------------------------------------------------
__global__ void elr_kernel(const float* __restrict__ h,
                           const float* __restrict__ al,
                           const float* __restrict__ ar,
                           float* __restrict__ el, float* __restrict__ er,
                           int N) {
    int t = blockIdx.x * 256 + threadIdx.x;
    if (t >= N * 4) return;
    int n = t >> 2, hh = t & 3;
    const float* hp = h + (size_t)n * 128 + hh * 32;
    float sl = 0.f, sr = 0.f;
#pragma unroll
    for (int j = 0; j < 32; j += 4) {
        float4 v = *(const float4*)(hp + j);
        float4 a = *(const float4*)(al + hh * 32 + j);
        float4 b = *(const float4*)(ar + hh * 32 + j);
        sl += v.x * a.x + v.y * a.y + v.z * a.z + v.w * a.w;
        sr += v.x * b.x + v.y * b.y + v.z * b.z + v.w * b.w;
    }
    el[t] = sl;
    er[t] = sr;
}

// ---------------------------------------------------------------------------
// edge pass 1: w[e,h] = exp(leaky_relu(el[src]+er[dst]));  s[dst,h] += w
// (no max-subtraction needed: |e| <~ 2, exp is stable in fp32;
//  alpha = exp(e)/sum exp(e) is mathematically identical to the reference)
// ---------------------------------------------------------------------------
__global__ void edge1_kernel(const int* __restrict__ src,
                             const int* __restrict__ dst,
                             const float* __restrict__ el,
                             const float* __restrict__ er,
                             float* __restrict__ w, float* __restrict__ s,
                             int E) {
    int e = blockIdx.x * 256 + threadIdx.x;
    if (e >= E) return;
    int si = src[e], di = dst[e];
    float4 l = *(const float4*)(el + (size_t)si * 4);
    float4 r = *(const float4*)(er + (size_t)di * 4);
    float4 wv;
    wv.x = __expf(lrelu(l.x + r.x));
    wv.y = __expf(lrelu(l.y + r.y));
    wv.z = __expf(lrelu(l.z + r.z));
    wv.w = __expf(lrelu(l.w + r.w));
    *(float4*)(w + (size_t)e * 4) = wv;
    float* sp = s + (size_t)di * 4;
    atomicAdd(sp + 0, wv.x);
    atomicAdd(sp + 1, wv.y);
    atomicAdd(sp + 2, wv.z);
    atomicAdd(sp + 3, wv.w);
}

// ---------------------------------------------------------------------------
// s -> 1/s (isolated nodes keep 0; they never appear as dst anyway)
// ---------------------------------------------------------------------------
__global__ void recip_kernel(float* __restrict__ s, int n) {
    int t = blockIdx.x * 256 + threadIdx.x;
    if (t >= n) return;
    float v = s[t];
    s[t] = v > 0.f ? 1.0f / v : 0.f;
}

// ---------------------------------------------------------------------------
// edge pass 2: 32 lanes per edge; lane d accumulates over heads:
//   out[dst,d] += 0.25 * sum_h (w[e,h]*rs[dst,h]) * hfeat[src, h*32+d]
// ---------------------------------------------------------------------------
__global__ __launch_bounds__(256) void edge2_kernel(
    const int* __restrict__ src, const int* __restrict__ dst,
    const float* __restrict__ h, const float* __restrict__ w,
    const float* __restrict__ rs, float* __restrict__ out, int E) {
    int t = blockIdx.x * 256 + threadIdx.x;
    int e = t >> 5;
    int d = t & 31;
    if (e >= E) return;
    int si = src[e], di = dst[e];
    float4 wv = *(const float4*)(w + (size_t)e * 4);
    float4 sv = *(const float4*)(rs + (size_t)di * 4);
    float a0 = wv.x * sv.x, a1 = wv.y * sv.y;
    float a2 = wv.z * sv.z, a3 = wv.w * sv.w;
    const float* hp = h + (size_t)si * 128;
    float acc = a0 * hp[d] + a1 * hp[32 + d] + a2 * hp[64 + d] + a3 * hp[96 + d];
    atomicAdd(out + (size_t)di * 32 + d, 0.25f * acc);
}

extern "C" void kernel_launch(void* const* d_in, const int* in_sizes, int n_in,
                              void* d_out, int out_size, void* d_ws,
                              size_t ws_size, hipStream_t stream) {
    const float* feat = (const float*)d_in[0];
    const float* Wm   = (const float*)d_in[1];
    const float* al   = (const float*)d_in[2];
    const float* ar   = (const float*)d_in[3];
    const float* bias = (const float*)d_in[4];
    const int*   src  = (const int*)d_in[5];
    const int*   dst  = (const int*)d_in[6];
    float* out = (float*)d_out;

    const int N = in_sizes[0] / 128;
    const int E = in_sizes[5];

    float* ws = (float*)d_ws;
    float* h  = ws;                       // N*128
    float* el = h + (size_t)N * 128;      // N*4
    float* er = el + (size_t)N * 4;       // N*4
    float* s  = er + (size_t)N * 4;       // N*4
    float* w  = s + (size_t)N * 4;        // E*4

    init_kernel<<<(N * 32 + 255) / 256, 256, 0, stream>>>(bias, out, s, N);
    gemm_kernel<<<(N + 127) / 128, 256, 0, stream>>>(feat, Wm, h, N);
    elr_kernel<<<(N * 4 + 255) / 256, 256, 0, stream>>>(h, al, ar, el, er, N);
    edge1_kernel<<<(E + 255) / 256, 256, 0, stream>>>(src, dst, el, er, w, s, E);
    recip_kernel<<<(N * 4 + 255) / 256, 256, 0, stream>>>(s, N * 4);
    edge2_kernel<<<(int)(((size_t)E * 32 + 255) / 256), 256, 0, stream>>>(
        src, dst, h, w, s, out, E);
}